// Round 12
// baseline (243.428 us; speedup 1.0000x reference)
//
#include <hip/hip_runtime.h>
#include <hip/hip_bf16.h>

// B=2, T=2048, E=1024, H=16, D=64. Inputs f32 (+ int32 mask), output f32.
// Internal bf16 MFMA pipeline.
// prep: ONE dispatch = embed convert + 4x weight transpose + mask bitmask.
// GEMMs: r7 ASYNC16 2-barrier structure; Q/K and out-GEMM computed as C^T
//        (swapped MFMA operands) so epilogue stores are bf16x4 / float4.
// Flash: r11 structure (bitmask); l-reduction deferred out of K-loop,
//        row-sum uses raw f32 p (no bf16 round-trip).

typedef __bf16 bf8_t  __attribute__((ext_vector_type(8)));
typedef __bf16 bf4_t  __attribute__((ext_vector_type(4)));
typedef float  f4_t   __attribute__((ext_vector_type(4)));

constexpr int Bb = 2, Tt = 2048, Hh = 16, Dd = 64;

#define ASYNC16(g, l)                                                        \
    __builtin_amdgcn_global_load_lds(                                        \
        (const __attribute__((address_space(1))) void*)(g),                  \
        (__attribute__((address_space(3))) void*)(l), 16, 0, 0)

#if __has_builtin(__builtin_amdgcn_exp2f)
#define EXP2F(x) __builtin_amdgcn_exp2f(x)
#else
#define EXP2F(x) exp2f(x)
#endif

// ---------------------------------------------------------------- prep
// blockIdx.x decode: [0,4096) transpose W (z>>10 = which matrix),
// [4096,5120) convert embed, [5120,6144) build bitmask.
__global__ __launch_bounds__(256) void prep_kernel(
    const float* __restrict__ embed, const int* __restrict__ mask,
    const float* __restrict__ w0, const float* __restrict__ w1,
    const float* __restrict__ w2, const float* __restrict__ w3,
    __bf16* __restrict__ o0, __bf16* __restrict__ o1,
    __bf16* __restrict__ o2, __bf16* __restrict__ o3,
    __bf16* __restrict__ Eb, unsigned* __restrict__ Mbits)
{
    int z = blockIdx.x;
    if (z < 4096) {
        const float* in; __bf16* out;
        switch (z >> 10) {
            case 0: in = w0; out = o0; break;
            case 1: in = w1; out = o1; break;
            case 2: in = w2; out = o2; break;
            default: in = w3; out = o3; break;
        }
        int rem = z & 1023;
        int bx = (rem & 31) * 32;      // n offset
        int by = (rem >> 5) * 32;      // k offset
        __shared__ float t[32][33];
        int x  = threadIdx.x & 31;
        int y0 = threadIdx.x >> 5;
        #pragma unroll
        for (int i = 0; i < 4; i++) {
            int y = y0 + i * 8;
            t[y][x] = in[(size_t)(by + y) * 1024 + bx + x];
        }
        __syncthreads();
        #pragma unroll
        for (int i = 0; i < 4; i++) {
            int y = y0 + i * 8;
            out[(size_t)(bx + y) * 1024 + by + x] = (__bf16)t[x][y];
        }
    } else if (z < 5120) {
        size_t base = (size_t)(z - 4096) * 4096;
        #pragma unroll
        for (int j = 0; j < 4; j++) {
            size_t i = base + j * 1024 + threadIdx.x * 4;
            float4 v = *reinterpret_cast<const float4*>(embed + i);
            bf4_t o = {(__bf16)v.x, (__bf16)v.y, (__bf16)v.z, (__bf16)v.w};
            *reinterpret_cast<bf4_t*>(Eb + i) = o;
        }
    } else {
        size_t g = (size_t)(z - 5120) * 256 + threadIdx.x;
        const int* mp = mask + g * 32;
        unsigned v = 0;
        #pragma unroll
        for (int i = 0; i < 8; i++) {
            int4 m4 = *reinterpret_cast<const int4*>(mp + i * 4);
            if (m4.x) v |= 1u << (i * 4 + 0);
            if (m4.y) v |= 1u << (i * 4 + 1);
            if (m4.z) v |= 1u << (i * 4 + 2);
            if (m4.w) v |= 1u << (i * 4 + 3);
        }
        Mbits[g] = v;
    }
}

// ---------------------------------------------------------------- GEMM body
// r7 ASYNC16 2-barrier structure. SWAP=true computes C^T (operands swapped):
//   lane holds gr = by*TM + wm*(TM/2) + im*16 + l16 (fixed),
//   gc0 = bx*128 + wn*64 + in_*16 + quad*4 (+r over regs)
//   -> vectorized stores along gc (bf16x4 for mode1, float4 for mode0).
// SWAP=false: normal C (used for V, mode 2 — vectorized along t already).
template <int TM, bool SWAP, typename OutT>
__device__ __forceinline__ void gemm_body(const __bf16* __restrict__ A,
                                          const __bf16* __restrict__ Bt,
                                          const float* __restrict__ bias,
                                          OutT* __restrict__ out,
                                          int mode, float oscale, int bx, int by)
{
    constexpr int NI = TM / 32;
    alignas(16) __shared__ __bf16 As[TM * 64];
    alignas(16) __shared__ __bf16 Bs[128 * 64];

    int tid  = threadIdx.x;
    int lane = tid & 63;
    int quad = lane >> 4;
    int l16  = lane & 15;
    int wave = tid >> 6;
    int wm   = wave >> 1, wn = wave & 1;

    f4_t acc[NI][4];
    #pragma unroll
    for (int i = 0; i < NI; i++)
        #pragma unroll
        for (int j = 0; j < 4; j++)
            acc[i][j] = f4_t{0.f, 0.f, 0.f, 0.f};

    for (int kt = 0; kt < 1024; kt += 64) {
        #pragma unroll
        for (int i = 0; i < TM / 32; i++) {
            int c   = tid + 256 * i;
            int row = c >> 3, j = c & 7;
            ASYNC16(A + (size_t)(by * TM + row) * 1024 + kt + ((j ^ (row & 7)) * 8),
                    &As[c * 8]);
        }
        #pragma unroll
        for (int i = 0; i < 4; i++) {
            int c   = tid + 256 * i;
            int row = c >> 3, j = c & 7;
            ASYNC16(Bt + (size_t)(bx * 128 + row) * 1024 + kt + ((j ^ (row & 7)) * 8),
                    &Bs[c * 8]);
        }
        __syncthreads();

        bf8_t af[2][NI], bfr[2][4];
        #pragma unroll
        for (int c = 0; c < 2; c++) {
            #pragma unroll
            for (int im = 0; im < NI; im++) {
                int row = wm * (TM / 2) + im * 16 + l16;
                af[c][im] = *reinterpret_cast<const bf8_t*>(
                    &As[row * 64 + (((c * 4 + quad) ^ (row & 7)) * 8)]);
            }
            #pragma unroll
            for (int in_ = 0; in_ < 4; in_++) {
                int row = wn * 64 + in_ * 16 + l16;
                bfr[c][in_] = *reinterpret_cast<const bf8_t*>(
                    &Bs[row * 64 + (((c * 4 + quad) ^ (row & 7)) * 8)]);
            }
        }
        #pragma unroll
        for (int c = 0; c < 2; c++)
            #pragma unroll
            for (int im = 0; im < NI; im++)
                #pragma unroll
                for (int in_ = 0; in_ < 4; in_++) {
                    if constexpr (SWAP)
                        acc[im][in_] = __builtin_amdgcn_mfma_f32_16x16x32_bf16(
                            bfr[c][in_], af[c][im], acc[im][in_], 0, 0, 0);
                    else
                        acc[im][in_] = __builtin_amdgcn_mfma_f32_16x16x32_bf16(
                            af[c][im], bfr[c][in_], acc[im][in_], 0, 0, 0);
                }
        __syncthreads();
    }

    if constexpr (SWAP) {
        #pragma unroll
        for (int im = 0; im < NI; im++) {
            int gr = by * TM + wm * (TM / 2) + im * 16 + l16;
            #pragma unroll
            for (int in_ = 0; in_ < 4; in_++) {
                int gc0 = bx * 128 + wn * 64 + in_ * 16 + quad * 4;
                f4_t bb = *reinterpret_cast<const f4_t*>(bias + gc0);
                if (mode == 0) {
                    f4_t v;
                    #pragma unroll
                    for (int r = 0; r < 4; r++)
                        v[r] = (acc[im][in_][r] + bb[r]) * oscale;
                    *reinterpret_cast<f4_t*>((float*)out + (size_t)gr * 1024 + gc0) = v;
                } else {   // mode 1: [B,H,T,D]
                    int b = gr >> 11, t = gr & 2047;
                    int h = gc0 >> 6, d0 = gc0 & 63;
                    bf4_t ov;
                    #pragma unroll
                    for (int r = 0; r < 4; r++)
                        ov[r] = (__bf16)((acc[im][in_][r] + bb[r]) * oscale);
                    *reinterpret_cast<bf4_t*>(
                        (__bf16*)out + ((size_t)(b * Hh + h) * Tt + t) * Dd + d0) = ov;
                }
            }
        }
    } else {
        #pragma unroll
        for (int im = 0; im < NI; im++) {
            #pragma unroll
            for (int in_ = 0; in_ < 4; in_++) {
                int gc  = bx * 128 + wn * 64 + in_ * 16 + l16;
                float bb = bias[gc];
                int gr0 = by * TM + wm * (TM / 2) + im * 16 + quad * 4;
                // mode 2: lane's 4 regs = 4 consecutive t at fixed (h,d)
                int b = gr0 >> 11, t0 = gr0 & 2047;
                int h = gc >> 6,  d = gc & 63;
                bf4_t ov;
                #pragma unroll
                for (int r = 0; r < 4; r++)
                    ov[r] = (__bf16)((acc[im][in_][r] + bb) * oscale);
                *reinterpret_cast<bf4_t*>(
                    (__bf16*)out + ((size_t)(b * Hh + h) * Dd + d) * Tt + t0) = ov;
            }
        }
    }
}

__global__ __launch_bounds__(256) void gemm_qkv_kernel(
    const __bf16* __restrict__ A,
    const __bf16* __restrict__ WqT, const __bf16* __restrict__ WkT, const __bf16* __restrict__ WvT,
    const float* __restrict__ bq,  const float* __restrict__ bk,  const float* __restrict__ bv,
    __bf16* __restrict__ Qo, __bf16* __restrict__ Ko, __bf16* __restrict__ Vo)
{
    // Q carries 0.125 * log2(e) so flash softmax runs in exp2 domain.
    if (blockIdx.z == 0)
        gemm_body<128, true, __bf16>(A, WqT, bq, Qo, 1, 0.18033688011112042f,
                                     blockIdx.x, blockIdx.y);
    else if (blockIdx.z == 1)
        gemm_body<128, true, __bf16>(A, WkT, bk, Ko, 1, 1.f,
                                     blockIdx.x, blockIdx.y);
    else
        gemm_body<128, false, __bf16>(A, WvT, bv, Vo, 2, 1.f,
                                      blockIdx.x, blockIdx.y);
}

__global__ __launch_bounds__(256) void gemm_out_kernel(
    const __bf16* __restrict__ A, const __bf16* __restrict__ Bt,
    const float* __restrict__ bias, float* __restrict__ out)
{
    gemm_body<64, true, float>(A, Bt, bias, out, 0, 1.f, blockIdx.x, blockIdx.y);
}

// ---------------------------------------------------------------- flash attn
// r11 structure: bitmask u64, dbuf LDS, one barrier/iter, reg-staged K/V.
// This round: per-lane l partial only in-loop (cross-lane reduction deferred
// to after the K-loop); row-sum uses raw f32 p.
__global__ __launch_bounds__(512, 4) void flash_kernel(
    const __bf16* __restrict__ Qb, const __bf16* __restrict__ Kb,
    const __bf16* __restrict__ Vb, const unsigned* __restrict__ Mbits,
    __bf16* __restrict__ Zb)
{
    alignas(16) __shared__ __bf16 Ks[2][64 * 64];   // swizzled, 8KB each
    alignas(16) __shared__ __bf16 Vs[2][64 * 64];
    alignas(16) __shared__ __bf16 Ps[8 * 16 * 72];  // per-wave P^T, 18KB

    int tid  = threadIdx.x;
    int lane = tid & 63;
    int wave = tid >> 6;
    int quad = lane >> 4;
    int l16  = lane & 15;
    int b = blockIdx.z, h = blockIdx.y;
    int bh = b * Hh + h;
    int qrow = blockIdx.x * 128 + wave * 16;

    int srow = tid >> 3, sj = tid & 7;
    const __bf16* kgp = Kb + ((size_t)bh * Tt + srow) * Dd + ((sj ^ (srow & 7)) * 8);
    const __bf16* vgp = Vb + ((size_t)bh * Dd + srow) * Tt + ((sj ^ (srow & 7)) * 8);
    const int sdst = tid * 8;

    bf8_t qf[2];
    #pragma unroll
    for (int c = 0; c < 2; c++)
        qf[c] = *reinterpret_cast<const bf8_t*>(
            Qb + ((size_t)bh * Tt + qrow + l16) * Dd + c * 32 + quad * 8);

    const unsigned* bmp = Mbits + ((size_t)b * Tt + qrow + l16) * 64;

    float l_i = 0.f;
    f4_t o[4];
    #pragma unroll
    for (int d = 0; d < 4; d++) o[d] = f4_t{0.f, 0.f, 0.f, 0.f};

    __bf16* pw = Ps + wave * 16 * 72;

    bf8_t kreg = *reinterpret_cast<const bf8_t*>(kgp);
    bf8_t vreg = *reinterpret_cast<const bf8_t*>(vgp);
    unsigned long long mreg = *reinterpret_cast<const unsigned long long*>(bmp);

    for (int kt = 0; kt < Tt; kt += 64) {
        int par = (kt >> 6) & 1;
        *reinterpret_cast<bf8_t*>(&Ks[par][sdst]) = kreg;
        *reinterpret_cast<bf8_t*>(&Vs[par][sdst]) = vreg;
        unsigned nib[4];
        #pragma unroll
        for (int n = 0; n < 4; n++)
            nib[n] = (unsigned)(mreg >> (n * 16 + quad * 4)) & 0xFu;
        __syncthreads();

        int ktn = (kt + 64 < Tt) ? kt + 64 : 0;
        kreg = *reinterpret_cast<const bf8_t*>(kgp + (size_t)ktn * Dd);
        vreg = *reinterpret_cast<const bf8_t*>(vgp + ktn);
        mreg = *reinterpret_cast<const unsigned long long*>(bmp + (ktn >> 5));

        f4_t s[4];
        #pragma unroll
        for (int n = 0; n < 4; n++) s[n] = f4_t{0.f, 0.f, 0.f, 0.f};
        #pragma unroll
        for (int c = 0; c < 2; c++)
            #pragma unroll
            for (int n = 0; n < 4; n++) {
                int krow = n * 16 + l16;
                bf8_t kf = *reinterpret_cast<const bf8_t*>(
                    &Ks[par][krow * 64 + (((c * 4 + quad) ^ (krow & 7)) * 8)]);
                s[n] = __builtin_amdgcn_mfma_f32_16x16x32_bf16(kf, qf[c], s[n], 0, 0, 0);
            }

        // p = mask-bit ? exp2(s) : 0; per-lane partial sum only (cross-lane
        // reduction deferred to after the loop); P^T -> LDS
        #pragma unroll
        for (int n = 0; n < 4; n++) {
            bf4_t pv4;
            #pragma unroll
            for (int r = 0; r < 4; r++) {
                float p = (nib[n] & (1u << r)) ? EXP2F(s[n][r]) : 0.f;
                l_i += p;
                pv4[r] = (__bf16)p;
            }
            *reinterpret_cast<bf4_t*>(&pw[l16 * 72 + n * 16 + quad * 4]) = pv4;
        }

        #pragma unroll
        for (int c = 0; c < 2; c++) {
            bf8_t pf = *reinterpret_cast<const bf8_t*>(
                &pw[l16 * 72 + c * 32 + quad * 8]);
            #pragma unroll
            for (int ds = 0; ds < 4; ds++) {
                int vrow = ds * 16 + l16;
                bf8_t vf = *reinterpret_cast<const bf8_t*>(
                    &Vs[par][vrow * 64 + (((c * 4 + quad) ^ (vrow & 7)) * 8)]);
                o[ds] = __builtin_amdgcn_mfma_f32_16x16x32_bf16(vf, pf, o[ds], 0, 0, 0);
            }
        }
        // no trailing barrier: next iter writes the other buffer.
    }

    // deferred cross-lane l reduction (quads of same query column)
    l_i += __shfl_xor(l_i, 16);
    l_i += __shfl_xor(l_i, 32);

    float inv = 1.f / fmaxf(l_i, 1e-30f);
    size_t zrow = ((size_t)b * Tt + qrow + l16) * 1024 + h * 64;
    #pragma unroll
    for (int ds = 0; ds < 4; ds++) {
        bf4_t ov;
        #pragma unroll
        for (int r = 0; r < 4; r++) ov[r] = (__bf16)(o[ds][r] * inv);
        *reinterpret_cast<bf4_t*>(Zb + zrow + ds * 16 + quad * 4) = ov;
    }
}

// ---------------------------------------------------------------- launch
extern "C" void kernel_launch(void* const* d_in, const int* in_sizes, int n_in,
                              void* d_out, int out_size, void* d_ws, size_t ws_size,
                              hipStream_t stream)
{
    (void)in_sizes; (void)n_in; (void)out_size; (void)ws_size;

    const float* embed = (const float*)d_in[0];
    const int*   mask  = (const int*)d_in[1];
    const float* Wq = (const float*)d_in[2];
    const float* bq = (const float*)d_in[3];
    const float* Wk = (const float*)d_in[4];
    const float* bk = (const float*)d_in[5];
    const float* Wv = (const float*)d_in[6];
    const float* bv = (const float*)d_in[7];
    const float* Wz = (const float*)d_in[8];
    const float* bz = (const float*)d_in[9];
    float* out = (float*)d_out;

    char* ws = (char*)d_ws;
    const size_t MB = (size_t)1024 * 1024;
    __bf16*   WqT = (__bf16*)(ws + 0 * MB);
    __bf16*   WkT = (__bf16*)(ws + 2 * MB);
    __bf16*   WvT = (__bf16*)(ws + 4 * MB);
    __bf16*   WzT = (__bf16*)(ws + 6 * MB);
    __bf16*   Eb  = (__bf16*)(ws + 8 * MB);
    __bf16*   Qb  = (__bf16*)(ws + 16 * MB);
    __bf16*   Kb  = (__bf16*)(ws + 24 * MB);
    __bf16*   Vb  = (__bf16*)(ws + 32 * MB);
    __bf16*   Zb  = (__bf16*)(ws + 40 * MB);
    unsigned* Mb  = (unsigned*)(ws + 48 * MB);   // bitmask, 1MB

    prep_kernel<<<dim3(6144), 256, 0, stream>>>(embed, mask, Wq, Wk, Wv, Wz,
                                                WqT, WkT, WvT, WzT, Eb, Mb);
    gemm_qkv_kernel<<<dim3(8, 32, 3), 256, 0, stream>>>(Eb, WqT, WkT, WvT,
                                                        bq, bk, bv, Qb, Kb, Vb);
    flash_kernel<<<dim3(16, Hh, Bb), 512, 0, stream>>>(Qb, Kb, Vb, Mb, Zb);
    gemm_out_kernel<<<dim3(8, 64, 1), 256, 0, stream>>>(Zb, WzT, bz, out);
}